// Round 9
// baseline (199.887 us; speedup 1.0000x reference)
//
#include <hip/hip_runtime.h>
#include <math.h>

#define N_NODES 1024
#define T_STEPS 36
#define KTILE   128          // k-nodes per attn V tile
#define VTSTR   136          // V^T LDS row stride (bf16): 128 data + 8 pad
#define WOS     72           // outproj Wo LDS stride (bf16)
#define OBS2    72           // outproj ob-tile LDS stride (bf16)
#define YSTR8   65           // proj8 V-transpose LDS row stride (uint32)

typedef __bf16  bf16x8 __attribute__((ext_vector_type(8)));
typedef float   f32x4  __attribute__((ext_vector_type(4)));

#define MFMA_BF16 __builtin_amdgcn_mfma_f32_16x16x32_bf16
#define PERM_HI 0x07060302u   // (a,b) -> hi16(b) | hi16(a)<<16
#define PERM_LO 0x05040100u   // (a,b) -> lo16(b) | lo16(a)<<16

__device__ __forceinline__ unsigned short bf16_rne(float f) {
    unsigned int u = __float_as_uint(f);
    u += 0x7FFFu + ((u >> 16) & 1u);
    return (unsigned short)(u >> 16);
}
__device__ __forceinline__ float bf16_tof(unsigned short h) {
    return __uint_as_float(((unsigned int)h) << 16);
}

// ---------------------------------------------------------------------------
// Kernel 1 (proj8): streaming projection — proj7's register economy with
// proj6's traffic-clean memory geometry.
// Block = 256 thr, tile 64 n x 2 t; thread = (hp=tid>>7, tl=(tid>>6)&1,
// nl=tid&63) -> every Q/K store instruction is wave-uniform in (th,plane):
// 64 lanes x consecutive n = 2KB dense full-line runs. Reads = 64 x 128B
// full lines. V transposed through 33KB LDS; phase-B writes 128B segments.
// ---------------------------------------------------------------------------
__global__ __launch_bounds__(256, 4) void proj8_kernel(
    const float* __restrict__ vin, const float* __restrict__ kin, const float* __restrict__ qin,
    const float* __restrict__ Wv, const float* __restrict__ Wk, const float* __restrict__ Wq,
    unsigned short* __restrict__ qhi, unsigned short* __restrict__ qlo,
    unsigned short* __restrict__ khi, unsigned short* __restrict__ klo,
    unsigned short* __restrict__ vthi, unsigned short* __restrict__ vtlo)
{
    __shared__ float sW[256];
    __shared__ unsigned int ys[128 * YSTR8];   // V only: [n_local*2+tl][hd*16+e]

    const int tid = threadIdx.x;
    const int mat = blockIdx.y;               // 0=v, 1=k, 2=q
    const int nt  = blockIdx.x & 15;          // 16 n-tiles of 64
    const int tt  = blockIdx.x >> 4;          // 0..17
    const int n0  = nt * 64, t0 = tt * 2;

    const float* in = (mat == 0) ? vin : (mat == 1) ? kin : qin;
    const float* W  = (mat == 0) ? Wv  : (mat == 1) ? Wk  : Wq;
    sW[tid] = W[tid];
    __syncthreads();

    const int hp = tid >> 7;                  // head-pair (wave-uniform)
    const int tl = (tid >> 6) & 1;            // t-local   (wave-uniform)
    const int nl = tid & 63;                  // node-local = lane
    const int n = n0 + nl, tcur = t0 + tl;
    const size_t ib = ((size_t)n * T_STEPS + tcur) * 64 + hp * 32;
    const float scale = (mat == 2) ? 0.18033688011112042f : 1.0f;  // log2(e)/8 on Q

    // read this thread's 2 heads (32 floats = one 128B line)
    float x[32];
    #pragma unroll
    for (int i = 0; i < 8; ++i) {
        float4 f = *(const float4*)(in + ib + 4*i);
        x[4*i] = f.x; x[4*i+1] = f.y; x[4*i+2] = f.z; x[4*i+3] = f.w;
    }

    if (mat != 0) {
        unsigned short* ohi = (mat == 1) ? khi : qhi;
        unsigned short* olo = (mat == 1) ? klo : qlo;
        #pragma unroll
        for (int hd2 = 0; hd2 < 2; ++hd2) {
            const float* xr = &x[hd2 * 16];
            union { unsigned short u[16]; uint4 v[2]; } hb, lb;
            #pragma unroll
            for (int e = 0; e < 16; ++e) {
                float4 w0 = *(const float4*)&sW[e*16+0],  w1 = *(const float4*)&sW[e*16+4];
                float4 w2 = *(const float4*)&sW[e*16+8],  w3 = *(const float4*)&sW[e*16+12];
                float a = xr[0]*w0.x;
                a = fmaf(xr[1],w0.y,a);  a = fmaf(xr[2],w0.z,a);  a = fmaf(xr[3],w0.w,a);
                a = fmaf(xr[4],w1.x,a);  a = fmaf(xr[5],w1.y,a);  a = fmaf(xr[6],w1.z,a);  a = fmaf(xr[7],w1.w,a);
                a = fmaf(xr[8],w2.x,a);  a = fmaf(xr[9],w2.y,a);  a = fmaf(xr[10],w2.z,a); a = fmaf(xr[11],w2.w,a);
                a = fmaf(xr[12],w3.x,a); a = fmaf(xr[13],w3.y,a); a = fmaf(xr[14],w3.z,a); a = fmaf(xr[15],w3.w,a);
                a *= scale;
                unsigned short hh = bf16_rne(a);
                hb.u[e] = hh; lb.u[e] = bf16_rne(a - bf16_tof(hh));
            }
            const int th = tcur * 4 + hp * 2 + hd2;      // wave-uniform
            const size_t off = ((size_t)th * N_NODES + n) * 16;
            *(uint4*)(ohi + off)     = hb.v[0];
            *(uint4*)(ohi + off + 8) = hb.v[1];
            *(uint4*)(olo + off)     = lb.v[0];
            *(uint4*)(olo + off + 8) = lb.v[1];
        }
    } else {
        // ---- V: project + pack into LDS, then transposed full-line stores ----
        #pragma unroll
        for (int hd2 = 0; hd2 < 2; ++hd2) {
            const float* xr = &x[hd2 * 16];
            unsigned int* yrow = &ys[(nl * 2 + tl) * YSTR8 + (hp * 2 + hd2) * 16];
            #pragma unroll
            for (int e = 0; e < 16; ++e) {
                float4 w0 = *(const float4*)&sW[e*16+0],  w1 = *(const float4*)&sW[e*16+4];
                float4 w2 = *(const float4*)&sW[e*16+8],  w3 = *(const float4*)&sW[e*16+12];
                float a = xr[0]*w0.x;
                a = fmaf(xr[1],w0.y,a);  a = fmaf(xr[2],w0.z,a);  a = fmaf(xr[3],w0.w,a);
                a = fmaf(xr[4],w1.x,a);  a = fmaf(xr[5],w1.y,a);  a = fmaf(xr[6],w1.z,a);  a = fmaf(xr[7],w1.w,a);
                a = fmaf(xr[8],w2.x,a);  a = fmaf(xr[9],w2.y,a);  a = fmaf(xr[10],w2.z,a); a = fmaf(xr[11],w2.w,a);
                a = fmaf(xr[12],w3.x,a); a = fmaf(xr[13],w3.y,a); a = fmaf(xr[14],w3.z,a); a = fmaf(xr[15],w3.w,a);
                unsigned short hh = bf16_rne(a);
                unsigned short ll = bf16_rne(a - bf16_tof(hh));
                yrow[e] = ((unsigned int)hh << 16) | ll;
            }
        }
        __syncthreads();
        // phase B: thread = (e=tid>>4, sel=(tid>>3)&1, oct=tid&7);
        // 8 passes over (tl2,hd); each (e,sel) group writes 8x16B = 128B line.
        const int e = tid >> 4, sel = (tid >> 3) & 1, oct = tid & 7;
        const unsigned int pm = sel ? PERM_LO : PERM_HI;
        unsigned short* obase = sel ? vtlo : vthi;
        #pragma unroll
        for (int p = 0; p < 8; ++p) {
            const int tl2 = p & 1, hd = p >> 1;
            unsigned int u[8];
            #pragma unroll
            for (int j = 0; j < 8; ++j)
                u[j] = ys[((oct*8 + j)*2 + tl2) * YSTR8 + hd*16 + e];
            uint4 o4;
            o4.x = __builtin_amdgcn_perm(u[1], u[0], pm);
            o4.y = __builtin_amdgcn_perm(u[3], u[2], pm);
            o4.z = __builtin_amdgcn_perm(u[5], u[4], pm);
            o4.w = __builtin_amdgcn_perm(u[7], u[6], pm);
            const int th = (t0 + tl2) * 4 + hd;
            unsigned short* dst = obase
                + ((size_t)th * 16 + e) * N_NODES + n0 + oct * 8;
            *(uint4*)dst = o4;
        }
    }
}

// ---------------------------------------------------------------------------
// Kernel 2 (attn_mfma5): unchanged from R7/R8 (~15-20us, off the top-5).
// K direct from global; V register-prefetch double-buffer; LDS 8.5KB.
// ---------------------------------------------------------------------------
__global__ __launch_bounds__(128, 5) void attn_mfma5_kernel(
    const unsigned short* __restrict__ qhi, const unsigned short* __restrict__ qlo,
    const unsigned short* __restrict__ khi, const unsigned short* __restrict__ klo,
    const unsigned short* __restrict__ vthi, const unsigned short* __restrict__ vtlo,
    unsigned short* __restrict__ obh, unsigned short* __restrict__ obl)
{
    __shared__ unsigned short vthi_s[16 * VTSTR];   // permuted node order per 32-chunk
    __shared__ unsigned short vtlo_s[16 * VTSTR];

    const int tid  = threadIdx.x;
    const int wave = tid >> 6, lane = tid & 63;
    const int m = lane & 15, quad = lane >> 4;

    const int bid = blockIdx.x;
    const int th  = bid % 144;          // th mod 8 stable -> XCD-local K/V reuse
    const int qb  = bid / 144;
    const int t   = th >> 2, hd = th & 3;
    const int q0  = qb * 64;
    const size_t base_th = (size_t)th * N_NODES;

    const bf16x8 bzero = {};
    bf16x8 b1q[2], b2q[2];
    #pragma unroll
    for (int g = 0; g < 2; ++g) {
        const int qrow = q0 + wave * 32 + g * 16 + m;
        b1q[g] = *(const bf16x8*)(qhi + (base_th + qrow) * 16 + (quad & 1) * 8);
        b2q[g] = (quad < 2)
            ? *(const bf16x8*)(qlo + (base_th + qrow) * 16 + (quad & 1) * 8) : bzero;
    }

    union { unsigned short su[8]; bf16x8 v; } onesu;
    #pragma unroll
    for (int i = 0; i < 8; ++i) onesu.su[i] = 0x3F80;
    const bf16x8 bones = onesu.v;

    f32x4 og[2]   = {{0.f,0.f,0.f,0.f},{0.f,0.f,0.f,0.f}};
    f32x4 lacc[2] = {{0.f,0.f,0.f,0.f},{0.f,0.f,0.f,0.f}};

    const unsigned short* kfrag = ((quad < 2) ? khi : klo)
        + (base_th + m) * 16 + (quad & 1) * 8;

    const int vd = (tid >> 2) & 15, vpart = tid & 3;
    const unsigned short* vsrc0 = (wave ? vtlo : vthi)
        + ((size_t)th * 16 + vd) * N_NODES + vpart * 32;
    unsigned short* vdst = (wave ? vtlo_s : vthi_s) + vd * VTSTR + vpart * 32;

    uint4 pf0, pf1, pf2, pf3;
    { const uint4* s = (const uint4*)vsrc0; pf0 = s[0]; pf1 = s[1]; pf2 = s[2]; pf3 = s[3]; }

    for (int kt = 0; kt < N_NODES; kt += KTILE) {
        __syncthreads();
        *(uint2*)&vdst[0]  = make_uint2(pf0.x, pf0.y);
        *(uint2*)&vdst[8]  = make_uint2(pf0.z, pf0.w);
        *(uint2*)&vdst[16] = make_uint2(pf1.x, pf1.y);
        *(uint2*)&vdst[24] = make_uint2(pf1.z, pf1.w);
        *(uint2*)&vdst[4]  = make_uint2(pf2.x, pf2.y);
        *(uint2*)&vdst[12] = make_uint2(pf2.z, pf2.w);
        *(uint2*)&vdst[20] = make_uint2(pf3.x, pf3.y);
        *(uint2*)&vdst[28] = make_uint2(pf3.z, pf3.w);
        __syncthreads();
        if (kt + KTILE < N_NODES) {
            const uint4* s = (const uint4*)(vsrc0 + kt + KTILE);
            pf0 = s[0]; pf1 = s[1]; pf2 = s[2]; pf3 = s[3];
        }

        #pragma unroll
        for (int c = 0; c < 4; ++c) {
            bf16x8 a0 = *(const bf16x8*)(kfrag + (size_t)(kt + (2*c    )*16) * 16);
            bf16x8 a1 = *(const bf16x8*)(kfrag + (size_t)(kt + (2*c + 1)*16) * 16);
            bf16x8 vh = *(const bf16x8*)&vthi_s[m * VTSTR + quad * 8 + c * 32];
            bf16x8 vl = *(const bf16x8*)&vtlo_s[m * VTSTR + quad * 8 + c * 32];
            #pragma unroll
            for (int g = 0; g < 2; ++g) {
                f32x4 s0 = MFMA_BF16(a0, b1q[g], (f32x4){0.f,0.f,0.f,0.f}, 0, 0, 0);
                s0 = MFMA_BF16(a0, b2q[g], s0, 0, 0, 0);
                f32x4 s1 = MFMA_BF16(a1, b1q[g], (f32x4){0.f,0.f,0.f,0.f}, 0, 0, 0);
                s1 = MFMA_BF16(a1, b2q[g], s1, 0, 0, 0);
                union { __bf16 b[8]; bf16x8 v; } ap;
                ap.b[0] = (__bf16)__builtin_amdgcn_exp2f(s0[0]);
                ap.b[1] = (__bf16)__builtin_amdgcn_exp2f(s0[1]);
                ap.b[2] = (__bf16)__builtin_amdgcn_exp2f(s0[2]);
                ap.b[3] = (__bf16)__builtin_amdgcn_exp2f(s0[3]);
                ap.b[4] = (__bf16)__builtin_amdgcn_exp2f(s1[0]);
                ap.b[5] = (__bf16)__builtin_amdgcn_exp2f(s1[1]);
                ap.b[6] = (__bf16)__builtin_amdgcn_exp2f(s1[2]);
                ap.b[7] = (__bf16)__builtin_amdgcn_exp2f(s1[3]);
                lacc[g] = MFMA_BF16(ap.v, bones, lacc[g], 0, 0, 0);
                og[g]   = MFMA_BF16(ap.v, vh, og[g], 0, 0, 0);
                og[g]   = MFMA_BF16(ap.v, vl, og[g], 0, 0, 0);
            }
        }
    }

    #pragma unroll
    for (int g = 0; g < 2; ++g) {
        #pragma unroll
        for (int r = 0; r < 4; ++r) {
            const float val = og[g][r] * __builtin_amdgcn_rcpf(lacc[g][r]);
            const int row = q0 + wave * 32 + g * 16 + quad * 4 + r;
            const size_t off = ((size_t)row * T_STEPS + t) * 64 + hd * 16 + m;
            unsigned short hh = bf16_rne(val);
            obh[off] = hh;
            obl[off] = bf16_rne(val - bf16_tof(hh));
        }
    }
}

// ---------------------------------------------------------------------------
// Kernel 3: MFMA output projection (unchanged).
// ---------------------------------------------------------------------------
__global__ __launch_bounds__(256) void outproj_mfma_kernel(
    const unsigned short* __restrict__ obh, const unsigned short* __restrict__ obl,
    const float* __restrict__ Wo, const float* __restrict__ bo,
    float* __restrict__ out)
{
    __shared__ unsigned short woh[64 * WOS], wol[64 * WOS];
    __shared__ unsigned short oth[64 * OBS2], otl[64 * OBS2];
    __shared__ float sb[64];
    const int tid = threadIdx.x;

    #pragma unroll
    for (int i = 0; i < 16; ++i) {
        int idx = tid + 256 * i;
        int r = idx >> 6, c = idx & 63;
        float w = Wo[idx];
        unsigned short hh = bf16_rne(w);
        woh[r * WOS + c] = hh;
        wol[r * WOS + c] = bf16_rne(w - bf16_tof(hh));
    }
    if (tid < 64) sb[tid] = bo[tid];

    const size_t p0 = (size_t)blockIdx.x * 64;
    #pragma unroll
    for (int i = 0; i < 2; ++i) {
        int idx = tid + 256 * i;
        int r = idx >> 3, c = (idx & 7) * 8;
        *(uint4*)&oth[r * OBS2 + c] = *(const uint4*)(obh + (p0 + r) * 64 + c);
        *(uint4*)&otl[r * OBS2 + c] = *(const uint4*)(obl + (p0 + r) * 64 + c);
    }
    __syncthreads();

    const int wave = tid >> 6, lane = tid & 63;
    const int m = lane & 15, quad = lane >> 4;
    const int r0 = wave * 16;

    bf16x8 ah[2], al[2];
    #pragma unroll
    for (int kh = 0; kh < 2; ++kh) {
        ah[kh] = *(const bf16x8*)&oth[(r0 + m) * OBS2 + kh * 32 + quad * 8];
        al[kh] = *(const bf16x8*)&otl[(r0 + m) * OBS2 + kh * 32 + quad * 8];
    }

    f32x4 acc[4] = {{0,0,0,0},{0,0,0,0},{0,0,0,0},{0,0,0,0}};
    #pragma unroll
    for (int jt = 0; jt < 4; ++jt) {
        #pragma unroll
        for (int kh = 0; kh < 2; ++kh) {
            bf16x8 bh = *(const bf16x8*)&woh[(jt * 16 + m) * WOS + kh * 32 + quad * 8];
            bf16x8 bl = *(const bf16x8*)&wol[(jt * 16 + m) * WOS + kh * 32 + quad * 8];
            acc[jt] = MFMA_BF16(ah[kh], bh, acc[jt], 0, 0, 0);
            acc[jt] = MFMA_BF16(al[kh], bh, acc[jt], 0, 0, 0);
            acc[jt] = MFMA_BF16(ah[kh], bl, acc[jt], 0, 0, 0);
        }
    }

    #pragma unroll
    for (int jt = 0; jt < 4; ++jt) {
        const float b = sb[jt * 16 + m];
        #pragma unroll
        for (int r = 0; r < 4; ++r)
            out[(p0 + r0 + quad * 4 + r) * 64 + jt * 16 + m] = acc[jt][r] + b;
    }
}

// ---------------------------------------------------------------------------
extern "C" void kernel_launch(void* const* d_in, const int* in_sizes, int n_in,
                              void* d_out, int out_size, void* d_ws, size_t ws_size,
                              hipStream_t stream)
{
    (void)in_sizes; (void)n_in; (void)out_size; (void)ws_size;
    const float* values = (const float*)d_in[0];
    const float* keys   = (const float*)d_in[1];
    const float* query  = (const float*)d_in[2];
    const float* Wv     = (const float*)d_in[3];
    const float* Wk     = (const float*)d_in[4];
    const float* Wq     = (const float*)d_in[5];
    const float* Wo     = (const float*)d_in[6];
    const float* bo     = (const float*)d_in[7];

    const size_t TOT = (size_t)144 * N_NODES * 16;   // 2,359,296 bf16 per plane
    unsigned short* ws16 = (unsigned short*)d_ws;
    unsigned short* qhi  = ws16;
    unsigned short* qlo  = ws16 + 1*TOT;
    unsigned short* khi  = ws16 + 2*TOT;
    unsigned short* klo  = ws16 + 3*TOT;
    unsigned short* vthi = ws16 + 4*TOT;
    unsigned short* vtlo = ws16 + 5*TOT;
    unsigned short* obh  = ws16 + 6*TOT;
    unsigned short* obl  = ws16 + 7*TOT;             // total ws = 8*TOT*2B = 37.75 MB

    // 288 = 16 n-tiles(64) x 18 t-tiles(2); y = matrix (0=v,1=k,2=q)
    proj8_kernel<<<dim3(288, 3), 256, 0, stream>>>(values, keys, query, Wv, Wk, Wq,
                                                   qhi, qlo, khi, klo, vthi, vtlo);
    attn_mfma5_kernel<<<dim3(16 * 144), 128, 0, stream>>>(qhi, qlo, khi, klo, vthi, vtlo,
                                                          obh, obl);
    outproj_mfma_kernel<<<dim3(576), 256, 0, stream>>>(obh, obl, Wo, bo, (float*)d_out);
}

// Round 10
// 133.492 us; speedup vs baseline: 1.4974x; 1.4974x over previous
//
#include <hip/hip_runtime.h>
#include <math.h>

#define N_NODES 1024
#define T_STEPS 36
#define KTILE   128          // k-nodes per attn V tile
#define VTSTR   136          // V^T LDS row stride (bf16): 128 data + 8 pad
#define WOS     72           // outproj Wo LDS stride (bf16)
#define OBS2    72           // outproj ob-tile LDS stride (bf16)
#define YSTR    67           // proj5 LDS row stride (uint32)

typedef __bf16  bf16x8 __attribute__((ext_vector_type(8)));
typedef float   f32x4  __attribute__((ext_vector_type(4)));

#define MFMA_BF16 __builtin_amdgcn_mfma_f32_16x16x32_bf16
#define PERM_HI 0x07060302u   // (a,b) -> hi16(b) | hi16(a)<<16
#define PERM_LO 0x05040100u   // (a,b) -> lo16(b) | lo16(a)<<16

__device__ __forceinline__ unsigned short bf16_rne(float f) {
    unsigned int u = __float_as_uint(f);
    u += 0x7FFFu + ((u >> 16) & 1u);
    return (unsigned short)(u >> 16);
}
__device__ __forceinline__ float bf16_tof(unsigned short h) {
    return __uint_as_float(((unsigned int)h) << 16);
}
// fp32 -> (hi bf16 << 16) | lo bf16, hi/lo split
__device__ __forceinline__ unsigned int split_pack(float a) {
    unsigned short hi = bf16_rne(a);
    unsigned short lo = bf16_rne(a - bf16_tof(hi));
    return ((unsigned int)hi << 16) | lo;
}

// ---------------------------------------------------------------------------
// Kernel 1 (proj5, EXACT R5 REVERT — empirically the fastest proj variant,
// ~30-35us; R7/R8 "improvements" regressed it to 66/87us).
// Block = 128 thr = tile (64 n) x (2 t), one matrix (blockIdx.y: 0=v,1=k,2=q).
// Phase A: thread = one (n,t) row, lanes cover consecutive rows -> coalesced
//          reads; stage packed hi|lo uints in LDS.
// Phase B: remap lanes to output order; v_perm splits hi/lo planes.
//   q/k out: [t][h][n][16]  (2KB contiguous per (t,hd,plane) chunk)
//   v out:   [t][h][d][n]   (128B contiguous per (t,hd,e) octet-group)
// ---------------------------------------------------------------------------
__global__ __launch_bounds__(128) void proj5_kernel(
    const float* __restrict__ vin, const float* __restrict__ kin, const float* __restrict__ qin,
    const float* __restrict__ Wv, const float* __restrict__ Wk, const float* __restrict__ Wq,
    unsigned short* __restrict__ qhi, unsigned short* __restrict__ qlo,
    unsigned short* __restrict__ khi, unsigned short* __restrict__ klo,
    unsigned short* __restrict__ vthi, unsigned short* __restrict__ vtlo)
{
    __shared__ float sW[256];
    __shared__ unsigned int ys[128 * YSTR];   // [row(nl*2+tl)][hd*16+e] packed hi|lo

    const int tid = threadIdx.x;
    const int mat = blockIdx.y;               // 0=v, 1=k, 2=q
    const int nt  = blockIdx.x & 15;
    const int tt  = blockIdx.x >> 4;          // 0..17
    const int n0  = nt * 64, t0 = tt * 2;

    const float* in = (mat == 0) ? vin : (mat == 1) ? kin : qin;
    const float* W  = (mat == 0) ? Wv  : (mat == 1) ? Wk  : Wq;
    sW[tid] = W[tid]; sW[tid + 128] = W[tid + 128];
    __syncthreads();

    // ---- Phase A: coalesced read + project + stage ----
    {
        const int nl = tid >> 1, tl = tid & 1;
        const size_t p = ((size_t)(n0 + nl)) * T_STEPS + (t0 + tl);
        const float4* src = (const float4*)(in + p * 64);
        float x[64];
        #pragma unroll
        for (int i = 0; i < 16; ++i) {
            float4 f = src[i];
            x[4*i] = f.x; x[4*i+1] = f.y; x[4*i+2] = f.z; x[4*i+3] = f.w;
        }
        const float scale = (mat == 2) ? 0.18033688011112042f : 1.0f;  // log2(e)/8 on Q
        unsigned int* yrow = &ys[tid * YSTR];
        #pragma unroll
        for (int e = 0; e < 16; ++e) {
            float4 w0 = *(const float4*)&sW[e*16+0],  w1 = *(const float4*)&sW[e*16+4];
            float4 w2 = *(const float4*)&sW[e*16+8],  w3 = *(const float4*)&sW[e*16+12];
            #pragma unroll
            for (int hd = 0; hd < 4; ++hd) {
                const float* xr = &x[hd*16];
                float a = xr[0]*w0.x;
                a = fmaf(xr[1],w0.y,a);  a = fmaf(xr[2],w0.z,a);  a = fmaf(xr[3],w0.w,a);
                a = fmaf(xr[4],w1.x,a);  a = fmaf(xr[5],w1.y,a);  a = fmaf(xr[6],w1.z,a);  a = fmaf(xr[7],w1.w,a);
                a = fmaf(xr[8],w2.x,a);  a = fmaf(xr[9],w2.y,a);  a = fmaf(xr[10],w2.z,a); a = fmaf(xr[11],w2.w,a);
                a = fmaf(xr[12],w3.x,a); a = fmaf(xr[13],w3.y,a); a = fmaf(xr[14],w3.z,a); a = fmaf(xr[15],w3.w,a);
                yrow[hd*16 + e] = split_pack(a * scale);
            }
        }
    }
    __syncthreads();

    // ---- Phase B: coalesced writes ----
    if (mat != 0) {
        unsigned short* ohi = (mat == 1) ? khi : qhi;
        unsigned short* olo = (mat == 1) ? klo : qlo;
        const int nl2 = tid >> 1, eh = tid & 1;
        #pragma unroll
        for (int pass = 0; pass < 8; ++pass) {
            const int tl2 = pass & 1, hd = pass >> 1;
            const unsigned int* yr = &ys[(nl2*2 + tl2) * YSTR + hd*16 + eh*8];
            unsigned int u0 = yr[0], u1 = yr[1], u2 = yr[2], u3 = yr[3];
            unsigned int u4 = yr[4], u5 = yr[5], u6 = yr[6], u7 = yr[7];
            uint4 hi4, lo4;
            hi4.x = __builtin_amdgcn_perm(u1, u0, PERM_HI);
            hi4.y = __builtin_amdgcn_perm(u3, u2, PERM_HI);
            hi4.z = __builtin_amdgcn_perm(u5, u4, PERM_HI);
            hi4.w = __builtin_amdgcn_perm(u7, u6, PERM_HI);
            lo4.x = __builtin_amdgcn_perm(u1, u0, PERM_LO);
            lo4.y = __builtin_amdgcn_perm(u3, u2, PERM_LO);
            lo4.z = __builtin_amdgcn_perm(u5, u4, PERM_LO);
            lo4.w = __builtin_amdgcn_perm(u7, u6, PERM_LO);
            const int th = (t0 + tl2) * 4 + hd;
            const size_t off = ((size_t)th * N_NODES + n0 + nl2) * 16 + eh * 8;
            *(uint4*)(ohi + off) = hi4;
            *(uint4*)(olo + off) = lo4;
        }
    } else {
        const int e = tid >> 3, ng = tid & 7;
        #pragma unroll
        for (int pass = 0; pass < 8; ++pass) {
            const int tl2 = pass & 1, hd = pass >> 1;
            unsigned int u[8];
            #pragma unroll
            for (int j = 0; j < 8; ++j)
                u[j] = ys[((ng*8 + j)*2 + tl2) * YSTR + hd*16 + e];
            uint4 hi4, lo4;
            hi4.x = __builtin_amdgcn_perm(u[1], u[0], PERM_HI);
            hi4.y = __builtin_amdgcn_perm(u[3], u[2], PERM_HI);
            hi4.z = __builtin_amdgcn_perm(u[5], u[4], PERM_HI);
            hi4.w = __builtin_amdgcn_perm(u[7], u[6], PERM_HI);
            lo4.x = __builtin_amdgcn_perm(u[1], u[0], PERM_LO);
            lo4.y = __builtin_amdgcn_perm(u[3], u[2], PERM_LO);
            lo4.z = __builtin_amdgcn_perm(u[5], u[4], PERM_LO);
            lo4.w = __builtin_amdgcn_perm(u[7], u[6], PERM_LO);
            const int th = (t0 + tl2) * 4 + hd;
            const size_t off = ((size_t)th * 16 + e) * N_NODES + n0 + ng * 8;
            *(uint4*)(vthi + off) = hi4;
            *(uint4*)(vtlo + off) = lo4;
        }
    }
}

// ---------------------------------------------------------------------------
// Kernel 2 (attn_mfma5): unchanged from R7/R8/R9 (~15-20us).
// K direct from global; V register-prefetch double-buffer; LDS 8.5KB.
// ---------------------------------------------------------------------------
__global__ __launch_bounds__(128, 5) void attn_mfma5_kernel(
    const unsigned short* __restrict__ qhi, const unsigned short* __restrict__ qlo,
    const unsigned short* __restrict__ khi, const unsigned short* __restrict__ klo,
    const unsigned short* __restrict__ vthi, const unsigned short* __restrict__ vtlo,
    unsigned short* __restrict__ obh, unsigned short* __restrict__ obl)
{
    __shared__ unsigned short vthi_s[16 * VTSTR];   // permuted node order per 32-chunk
    __shared__ unsigned short vtlo_s[16 * VTSTR];

    const int tid  = threadIdx.x;
    const int wave = tid >> 6, lane = tid & 63;
    const int m = lane & 15, quad = lane >> 4;

    const int bid = blockIdx.x;
    const int th  = bid % 144;          // th mod 8 stable -> XCD-local K/V reuse
    const int qb  = bid / 144;
    const int t   = th >> 2, hd = th & 3;
    const int q0  = qb * 64;
    const size_t base_th = (size_t)th * N_NODES;

    const bf16x8 bzero = {};
    bf16x8 b1q[2], b2q[2];
    #pragma unroll
    for (int g = 0; g < 2; ++g) {
        const int qrow = q0 + wave * 32 + g * 16 + m;
        b1q[g] = *(const bf16x8*)(qhi + (base_th + qrow) * 16 + (quad & 1) * 8);
        b2q[g] = (quad < 2)
            ? *(const bf16x8*)(qlo + (base_th + qrow) * 16 + (quad & 1) * 8) : bzero;
    }

    union { unsigned short su[8]; bf16x8 v; } onesu;
    #pragma unroll
    for (int i = 0; i < 8; ++i) onesu.su[i] = 0x3F80;
    const bf16x8 bones = onesu.v;

    f32x4 og[2]   = {{0.f,0.f,0.f,0.f},{0.f,0.f,0.f,0.f}};
    f32x4 lacc[2] = {{0.f,0.f,0.f,0.f},{0.f,0.f,0.f,0.f}};

    const unsigned short* kfrag = ((quad < 2) ? khi : klo)
        + (base_th + m) * 16 + (quad & 1) * 8;

    const int vd = (tid >> 2) & 15, vpart = tid & 3;
    const unsigned short* vsrc0 = (wave ? vtlo : vthi)
        + ((size_t)th * 16 + vd) * N_NODES + vpart * 32;
    unsigned short* vdst = (wave ? vtlo_s : vthi_s) + vd * VTSTR + vpart * 32;

    uint4 pf0, pf1, pf2, pf3;
    { const uint4* s = (const uint4*)vsrc0; pf0 = s[0]; pf1 = s[1]; pf2 = s[2]; pf3 = s[3]; }

    for (int kt = 0; kt < N_NODES; kt += KTILE) {
        __syncthreads();
        *(uint2*)&vdst[0]  = make_uint2(pf0.x, pf0.y);
        *(uint2*)&vdst[8]  = make_uint2(pf0.z, pf0.w);
        *(uint2*)&vdst[16] = make_uint2(pf1.x, pf1.y);
        *(uint2*)&vdst[24] = make_uint2(pf1.z, pf1.w);
        *(uint2*)&vdst[4]  = make_uint2(pf2.x, pf2.y);
        *(uint2*)&vdst[12] = make_uint2(pf2.z, pf2.w);
        *(uint2*)&vdst[20] = make_uint2(pf3.x, pf3.y);
        *(uint2*)&vdst[28] = make_uint2(pf3.z, pf3.w);
        __syncthreads();
        if (kt + KTILE < N_NODES) {
            const uint4* s = (const uint4*)(vsrc0 + kt + KTILE);
            pf0 = s[0]; pf1 = s[1]; pf2 = s[2]; pf3 = s[3];
        }

        #pragma unroll
        for (int c = 0; c < 4; ++c) {
            bf16x8 a0 = *(const bf16x8*)(kfrag + (size_t)(kt + (2*c    )*16) * 16);
            bf16x8 a1 = *(const bf16x8*)(kfrag + (size_t)(kt + (2*c + 1)*16) * 16);
            bf16x8 vh = *(const bf16x8*)&vthi_s[m * VTSTR + quad * 8 + c * 32];
            bf16x8 vl = *(const bf16x8*)&vtlo_s[m * VTSTR + quad * 8 + c * 32];
            #pragma unroll
            for (int g = 0; g < 2; ++g) {
                f32x4 s0 = MFMA_BF16(a0, b1q[g], (f32x4){0.f,0.f,0.f,0.f}, 0, 0, 0);
                s0 = MFMA_BF16(a0, b2q[g], s0, 0, 0, 0);
                f32x4 s1 = MFMA_BF16(a1, b1q[g], (f32x4){0.f,0.f,0.f,0.f}, 0, 0, 0);
                s1 = MFMA_BF16(a1, b2q[g], s1, 0, 0, 0);
                union { __bf16 b[8]; bf16x8 v; } ap;
                ap.b[0] = (__bf16)__builtin_amdgcn_exp2f(s0[0]);
                ap.b[1] = (__bf16)__builtin_amdgcn_exp2f(s0[1]);
                ap.b[2] = (__bf16)__builtin_amdgcn_exp2f(s0[2]);
                ap.b[3] = (__bf16)__builtin_amdgcn_exp2f(s0[3]);
                ap.b[4] = (__bf16)__builtin_amdgcn_exp2f(s1[0]);
                ap.b[5] = (__bf16)__builtin_amdgcn_exp2f(s1[1]);
                ap.b[6] = (__bf16)__builtin_amdgcn_exp2f(s1[2]);
                ap.b[7] = (__bf16)__builtin_amdgcn_exp2f(s1[3]);
                lacc[g] = MFMA_BF16(ap.v, bones, lacc[g], 0, 0, 0);
                og[g]   = MFMA_BF16(ap.v, vh, og[g], 0, 0, 0);
                og[g]   = MFMA_BF16(ap.v, vl, og[g], 0, 0, 0);
            }
        }
    }

    #pragma unroll
    for (int g = 0; g < 2; ++g) {
        #pragma unroll
        for (int r = 0; r < 4; ++r) {
            const float val = og[g][r] * __builtin_amdgcn_rcpf(lacc[g][r]);
            const int row = q0 + wave * 32 + g * 16 + quad * 4 + r;
            const size_t off = ((size_t)row * T_STEPS + t) * 64 + hd * 16 + m;
            unsigned short hh = bf16_rne(val);
            obh[off] = hh;
            obl[off] = bf16_rne(val - bf16_tof(hh));
        }
    }
}

// ---------------------------------------------------------------------------
// Kernel 3: MFMA output projection (unchanged).
// ---------------------------------------------------------------------------
__global__ __launch_bounds__(256) void outproj_mfma_kernel(
    const unsigned short* __restrict__ obh, const unsigned short* __restrict__ obl,
    const float* __restrict__ Wo, const float* __restrict__ bo,
    float* __restrict__ out)
{
    __shared__ unsigned short woh[64 * WOS], wol[64 * WOS];
    __shared__ unsigned short oth[64 * OBS2], otl[64 * OBS2];
    __shared__ float sb[64];
    const int tid = threadIdx.x;

    #pragma unroll
    for (int i = 0; i < 16; ++i) {
        int idx = tid + 256 * i;
        int r = idx >> 6, c = idx & 63;
        float w = Wo[idx];
        unsigned short hh = bf16_rne(w);
        woh[r * WOS + c] = hh;
        wol[r * WOS + c] = bf16_rne(w - bf16_tof(hh));
    }
    if (tid < 64) sb[tid] = bo[tid];

    const size_t p0 = (size_t)blockIdx.x * 64;
    #pragma unroll
    for (int i = 0; i < 2; ++i) {
        int idx = tid + 256 * i;
        int r = idx >> 3, c = (idx & 7) * 8;
        *(uint4*)&oth[r * OBS2 + c] = *(const uint4*)(obh + (p0 + r) * 64 + c);
        *(uint4*)&otl[r * OBS2 + c] = *(const uint4*)(obl + (p0 + r) * 64 + c);
    }
    __syncthreads();

    const int wave = tid >> 6, lane = tid & 63;
    const int m = lane & 15, quad = lane >> 4;
    const int r0 = wave * 16;

    bf16x8 ah[2], al[2];
    #pragma unroll
    for (int kh = 0; kh < 2; ++kh) {
        ah[kh] = *(const bf16x8*)&oth[(r0 + m) * OBS2 + kh * 32 + quad * 8];
        al[kh] = *(const bf16x8*)&otl[(r0 + m) * OBS2 + kh * 32 + quad * 8];
    }

    f32x4 acc[4] = {{0,0,0,0},{0,0,0,0},{0,0,0,0},{0,0,0,0}};
    #pragma unroll
    for (int jt = 0; jt < 4; ++jt) {
        #pragma unroll
        for (int kh = 0; kh < 2; ++kh) {
            bf16x8 bh = *(const bf16x8*)&woh[(jt * 16 + m) * WOS + kh * 32 + quad * 8];
            bf16x8 bl = *(const bf16x8*)&wol[(jt * 16 + m) * WOS + kh * 32 + quad * 8];
            acc[jt] = MFMA_BF16(ah[kh], bh, acc[jt], 0, 0, 0);
            acc[jt] = MFMA_BF16(al[kh], bh, acc[jt], 0, 0, 0);
            acc[jt] = MFMA_BF16(ah[kh], bl, acc[jt], 0, 0, 0);
        }
    }

    #pragma unroll
    for (int jt = 0; jt < 4; ++jt) {
        const float b = sb[jt * 16 + m];
        #pragma unroll
        for (int r = 0; r < 4; ++r)
            out[(p0 + r0 + quad * 4 + r) * 64 + jt * 16 + m] = acc[jt][r] + b;
    }
}

// ---------------------------------------------------------------------------
extern "C" void kernel_launch(void* const* d_in, const int* in_sizes, int n_in,
                              void* d_out, int out_size, void* d_ws, size_t ws_size,
                              hipStream_t stream)
{
    (void)in_sizes; (void)n_in; (void)out_size; (void)ws_size;
    const float* values = (const float*)d_in[0];
    const float* keys   = (const float*)d_in[1];
    const float* query  = (const float*)d_in[2];
    const float* Wv     = (const float*)d_in[3];
    const float* Wk     = (const float*)d_in[4];
    const float* Wq     = (const float*)d_in[5];
    const float* Wo     = (const float*)d_in[6];
    const float* bo     = (const float*)d_in[7];

    const size_t TOT = (size_t)144 * N_NODES * 16;   // 2,359,296 bf16 per plane
    unsigned short* ws16 = (unsigned short*)d_ws;
    unsigned short* qhi  = ws16;
    unsigned short* qlo  = ws16 + 1*TOT;
    unsigned short* khi  = ws16 + 2*TOT;
    unsigned short* klo  = ws16 + 3*TOT;
    unsigned short* vthi = ws16 + 4*TOT;
    unsigned short* vtlo = ws16 + 5*TOT;
    unsigned short* obh  = ws16 + 6*TOT;
    unsigned short* obl  = ws16 + 7*TOT;             // total ws = 8*TOT*2B = 37.75 MB

    // 288 = 16 n-tiles x 18 t-tiles; y = matrix (0=v,1=k,2=q)
    proj5_kernel<<<dim3(288, 3), 128, 0, stream>>>(values, keys, query, Wv, Wk, Wq,
                                                   qhi, qlo, khi, klo, vthi, vtlo);
    attn_mfma5_kernel<<<dim3(16 * 144), 128, 0, stream>>>(qhi, qlo, khi, klo, vthi, vtlo,
                                                          obh, obl);
    outproj_mfma_kernel<<<dim3(576), 256, 0, stream>>>(obh, obl, Wo, bo, (float*)d_out);
}